// Round 3
// baseline (7301.093 us; speedup 1.0000x reference)
//
#include <hip/hip_runtime.h>

// LightGCN conv via coarse radix partition (64-row buckets) + LDS accumulate.
// Stages: count_hist -> exscan -> partition (block-aggregated claims) ->
//         bucket_accumulate (one block per 64 output rows, LDS f32 atomics).

constexpr int DIM   = 64;
constexpr int RB    = 64;      // output rows per bucket (dlow = 6 bits)
constexpr int CHUNK = 16384;   // edges per partition block

// ---------------- fallback (round-1) atomic kernel ----------------
__global__ void lightgcn_scatter_atomic(const float* __restrict__ user_emb,
                                        const float* __restrict__ item_emb,
                                        const int* __restrict__ rows,
                                        const int* __restrict__ cols,
                                        const float* __restrict__ vals,
                                        float* __restrict__ user_out,
                                        float* __restrict__ item_out,
                                        int nnz) {
    const int lane   = threadIdx.x & 63;
    const int wave   = (blockIdx.x * blockDim.x + threadIdx.x) >> 6;
    const int nwaves = (gridDim.x * blockDim.x) >> 6;
    for (int e = wave; e < nnz; e += nwaves) {
        const int r = rows[e];
        const int c = cols[e];
        const float v = vals[e];
        atomicAdd(&user_out[(size_t)r * DIM + lane], v * item_emb[(size_t)c * DIM + lane]);
        atomicAdd(&item_out[(size_t)c * DIM + lane], v * user_emb[(size_t)r * DIM + lane]);
    }
}

// ---------------- stage 1: bucket histogram (block-local LDS) ----------------
__global__ void count_hist(const int* __restrict__ rows,
                           const int* __restrict__ cols,
                           int nnz, int K_i, int K_all,
                           int* __restrict__ counts) {
    extern __shared__ int h[];   // K_all ints
    for (int t = threadIdx.x; t < K_all; t += blockDim.x) h[t] = 0;
    __syncthreads();
    int i = blockIdx.x * blockDim.x + threadIdx.x;
    const int stride = gridDim.x * blockDim.x;
    for (; i < nnz; i += stride) {
        atomicAdd(&h[cols[i] >> 6], 1);              // item bucket
        atomicAdd(&h[K_i + (rows[i] >> 6)], 1);      // user bucket
    }
    __syncthreads();
    for (int t = threadIdx.x; t < K_all; t += blockDim.x)
        if (h[t]) atomicAdd(&counts[t], h[t]);
}

// ---------------- stage 2: exclusive scan over K_all buckets (1 block) -------
__global__ void exscan_small(const int* __restrict__ counts, int n,
                             int* __restrict__ base, int* __restrict__ cursor) {
    __shared__ int s[1024];
    __shared__ int carry_s;
    if (threadIdx.x == 0) carry_s = 0;
    __syncthreads();
    for (int b0 = 0; b0 < n; b0 += 1024) {
        const int i = b0 + (int)threadIdx.x;
        const int x = (i < n) ? counts[i] : 0;
        s[threadIdx.x] = x;
        __syncthreads();
        for (int off = 1; off < 1024; off <<= 1) {
            const int t = (threadIdx.x >= (unsigned)off) ? s[threadIdx.x - off] : 0;
            __syncthreads();
            s[threadIdx.x] += t;
            __syncthreads();
        }
        const int ex = carry_s + s[threadIdx.x] - x;
        if (i < n) { base[i] = ex; cursor[i] = ex; }
        const int tot = s[1023];
        __syncthreads();
        if (threadIdx.x == 0) carry_s += tot;
        __syncthreads();
    }
}

// ---------------- stage 3: partition (block-aggregated slot claims) ----------
__global__ __launch_bounds__(256)
void partition_edges(const int* __restrict__ rows,
                     const int* __restrict__ cols,
                     const float* __restrict__ vals,
                     int nnz, int K_i, int K_all,
                     int* __restrict__ cursor, uint2* __restrict__ pairs) {
    extern __shared__ int h[];   // K_all ints
    const int c0 = blockIdx.x * CHUNK;
    const int c1 = min(c0 + CHUNK, nnz);
    for (int t = threadIdx.x; t < K_all; t += blockDim.x) h[t] = 0;
    __syncthreads();
    // sweep A: local histogram
    for (int e = c0 + (int)threadIdx.x; e < c1; e += blockDim.x) {
        atomicAdd(&h[cols[e] >> 6], 1);
        atomicAdd(&h[K_i + (rows[e] >> 6)], 1);
    }
    __syncthreads();
    // claim: one global atomic per nonzero bucket; h[t] becomes global base
    for (int t = threadIdx.x; t < K_all; t += blockDim.x) {
        const int cnt = h[t];
        if (cnt) h[t] = atomicAdd(&cursor[t], cnt);
    }
    __syncthreads();
    // sweep B: scatter pairs into claimed (mostly sequential) segments
    for (int e = c0 + (int)threadIdx.x; e < c1; e += blockDim.x) {
        const int r = rows[e];
        const int c = cols[e];
        const unsigned vb = __float_as_uint(vals[e]);
        const int si = atomicAdd(&h[c >> 6], 1);            // item side: dest=c, nbr=r
        pairs[si] = make_uint2(((unsigned)(c & 63) << 17) | (unsigned)r, vb);
        const int su = atomicAdd(&h[K_i + (r >> 6)], 1);    // user side: dest=r, nbr=c
        pairs[su] = make_uint2(((unsigned)(r & 63) << 17) | (unsigned)c, vb);
    }
}

// ---------------- stage 4: per-bucket LDS accumulate ----------------
__global__ __launch_bounds__(128)
void bucket_accumulate(const float* __restrict__ user_emb,
                       const float* __restrict__ item_emb,
                       const uint2* __restrict__ pairs,
                       const int* __restrict__ base,
                       const int* __restrict__ counts,
                       int K_i, int n_users, int n_items,
                       float* __restrict__ user_out, float* __restrict__ item_out) {
    __shared__ float acc[RB * DIM];   // 16 KiB
    const int b = blockIdx.x;
    const bool item_side = (b < K_i);
    const int bb = item_side ? b : (b - K_i);
    const int base_row = bb * RB;
    const int nrows_all = item_side ? n_items : n_users;
    const float* __restrict__ emb = item_side ? user_emb : item_emb;
    float* __restrict__ out = item_side ? item_out : user_out;

    for (int i = threadIdx.x; i < RB * DIM; i += blockDim.x) acc[i] = 0.f;
    __syncthreads();

    const int start = base[b];
    const int end   = start + counts[b];
    const int lane  = threadIdx.x & 63;
    const int wid   = threadIdx.x >> 6;
    const int nw    = blockDim.x >> 6;

    const int total = end - start;
    const int per   = (total + nw - 1) / nw;
    const int ws    = start + wid * per;
    const int we    = min(ws + per, end);

    int e = ws;
    for (; e + 4 <= we; e += 4) {
        const uint2 p0 = pairs[e + 0];
        const uint2 p1 = pairs[e + 1];
        const uint2 p2 = pairs[e + 2];
        const uint2 p3 = pairs[e + 3];
        const float g0 = emb[(size_t)(p0.x & 0x1FFFFu) * DIM + lane];
        const float g1 = emb[(size_t)(p1.x & 0x1FFFFu) * DIM + lane];
        const float g2 = emb[(size_t)(p2.x & 0x1FFFFu) * DIM + lane];
        const float g3 = emb[(size_t)(p3.x & 0x1FFFFu) * DIM + lane];
        atomicAdd(&acc[((p0.x >> 17) << 6) + lane], __uint_as_float(p0.y) * g0);
        atomicAdd(&acc[((p1.x >> 17) << 6) + lane], __uint_as_float(p1.y) * g1);
        atomicAdd(&acc[((p2.x >> 17) << 6) + lane], __uint_as_float(p2.y) * g2);
        atomicAdd(&acc[((p3.x >> 17) << 6) + lane], __uint_as_float(p3.y) * g3);
    }
    for (; e < we; ++e) {
        const uint2 p = pairs[e];
        const float g = emb[(size_t)(p.x & 0x1FFFFu) * DIM + lane];
        atomicAdd(&acc[((p.x >> 17) << 6) + lane], __uint_as_float(p.y) * g);
    }
    __syncthreads();

    const int nrows = min(RB, nrows_all - base_row);
    for (int i = threadIdx.x; i < nrows * DIM; i += blockDim.x)
        out[(size_t)base_row * DIM + i] = acc[i];
}

extern "C" void kernel_launch(void* const* d_in, const int* in_sizes, int n_in,
                              void* d_out, int out_size, void* d_ws, size_t ws_size,
                              hipStream_t stream) {
    const float* user_emb = (const float*)d_in[0];
    const float* item_emb = (const float*)d_in[1];
    const int*   rows     = (const int*)d_in[2];
    const int*   cols     = (const int*)d_in[3];
    const float* vals     = (const float*)d_in[4];

    const int nnz     = in_sizes[2];
    const int n_users = in_sizes[0] / DIM;
    const int n_items = in_sizes[1] / DIM;

    float* user_out = (float*)d_out;
    float* item_out = (float*)d_out + (size_t)in_sizes[0];

    const int K_i   = (n_items + RB - 1) / RB;
    const int K_u   = (n_users + RB - 1) / RB;
    const int K_all = K_i + K_u;

    // Workspace: counts | base | cursor (each padded) | pairs[2*nnz]
    const size_t Kpad      = ((size_t)K_all + 1023) & ~(size_t)1023;
    const size_t meta_ints = 3 * Kpad;
    const size_t pairs_off = (meta_ints * sizeof(int) + 127) & ~(size_t)127;
    const size_t need      = pairs_off + 2 * (size_t)nnz * sizeof(uint2);

    if (ws_size < need || n_users > 131072 || n_items > 131072) {
        hipMemsetAsync(d_out, 0, (size_t)out_size * sizeof(float), stream);
        lightgcn_scatter_atomic<<<2048, 256, 0, stream>>>(user_emb, item_emb, rows,
                                                          cols, vals, user_out,
                                                          item_out, nnz);
        return;
    }

    int* counts = (int*)d_ws;
    int* bases  = counts + Kpad;
    int* cursor = bases + Kpad;
    uint2* pairs = (uint2*)((char*)d_ws + pairs_off);

    hipMemsetAsync(counts, 0, (size_t)K_all * sizeof(int), stream);

    const size_t hist_bytes = (size_t)K_all * sizeof(int);
    count_hist<<<1024, 256, hist_bytes, stream>>>(rows, cols, nnz, K_i, K_all, counts);
    exscan_small<<<1, 1024, 0, stream>>>(counts, K_all, bases, cursor);

    const int part_blocks = (nnz + CHUNK - 1) / CHUNK;
    partition_edges<<<part_blocks, 256, hist_bytes, stream>>>(rows, cols, vals, nnz,
                                                              K_i, K_all, cursor, pairs);

    bucket_accumulate<<<K_all, 128, 0, stream>>>(user_emb, item_emb, pairs, bases,
                                                 counts, K_i, n_users, n_items,
                                                 user_out, item_out);
}

// Round 4
// 6872.257 us; speedup vs baseline: 1.0624x; 1.0624x over previous
//
#include <hip/hip_runtime.h>

// LightGCN conv via coarse radix partition (64-row buckets) + split LDS accumulate.
// Stages: count_hist -> exscan -> partition (block-aggregated claims) ->
//         bucket_accumulate_split (SPLIT blocks per bucket, LDS partials,
//         global f32 atomic merge into zeroed d_out).

constexpr int DIM   = 64;
constexpr int RB    = 64;      // output rows per bucket (low 6 bits of dest id)
constexpr int CHUNK = 16384;   // edges per partition block
constexpr int SPLIT = 8;       // blocks per bucket in accumulate

// ---------------- fallback (round-1) atomic kernel ----------------
__global__ void lightgcn_scatter_atomic(const float* __restrict__ user_emb,
                                        const float* __restrict__ item_emb,
                                        const int* __restrict__ rows,
                                        const int* __restrict__ cols,
                                        const float* __restrict__ vals,
                                        float* __restrict__ user_out,
                                        float* __restrict__ item_out,
                                        int nnz) {
    const int lane   = threadIdx.x & 63;
    const int wave   = (blockIdx.x * blockDim.x + threadIdx.x) >> 6;
    const int nwaves = (gridDim.x * blockDim.x) >> 6;
    for (int e = wave; e < nnz; e += nwaves) {
        const int r = rows[e];
        const int c = cols[e];
        const float v = vals[e];
        atomicAdd(&user_out[(size_t)r * DIM + lane], v * item_emb[(size_t)c * DIM + lane]);
        atomicAdd(&item_out[(size_t)c * DIM + lane], v * user_emb[(size_t)r * DIM + lane]);
    }
}

// ---------------- stage 1: bucket histogram (block-local LDS) ----------------
__global__ void count_hist(const int* __restrict__ rows,
                           const int* __restrict__ cols,
                           int nnz, int K_i, int K_all,
                           int* __restrict__ counts) {
    extern __shared__ int h[];   // K_all ints
    for (int t = threadIdx.x; t < K_all; t += blockDim.x) h[t] = 0;
    __syncthreads();
    int i = blockIdx.x * blockDim.x + threadIdx.x;
    const int stride = gridDim.x * blockDim.x;
    for (; i < nnz; i += stride) {
        atomicAdd(&h[cols[i] >> 6], 1);              // item bucket
        atomicAdd(&h[K_i + (rows[i] >> 6)], 1);      // user bucket
    }
    __syncthreads();
    for (int t = threadIdx.x; t < K_all; t += blockDim.x)
        if (h[t]) atomicAdd(&counts[t], h[t]);
}

// ---------------- stage 2: exclusive scan over K_all buckets (1 block) -------
__global__ void exscan_small(const int* __restrict__ counts, int n,
                             int* __restrict__ base, int* __restrict__ cursor) {
    __shared__ int s[1024];
    __shared__ int carry_s;
    if (threadIdx.x == 0) carry_s = 0;
    __syncthreads();
    for (int b0 = 0; b0 < n; b0 += 1024) {
        const int i = b0 + (int)threadIdx.x;
        const int x = (i < n) ? counts[i] : 0;
        s[threadIdx.x] = x;
        __syncthreads();
        for (int off = 1; off < 1024; off <<= 1) {
            const int t = (threadIdx.x >= (unsigned)off) ? s[threadIdx.x - off] : 0;
            __syncthreads();
            s[threadIdx.x] += t;
            __syncthreads();
        }
        const int ex = carry_s + s[threadIdx.x] - x;
        if (i < n) { base[i] = ex; cursor[i] = ex; }
        const int tot = s[1023];
        __syncthreads();
        if (threadIdx.x == 0) carry_s += tot;
        __syncthreads();
    }
}

// ---------------- stage 3: partition (block-aggregated slot claims) ----------
__global__ __launch_bounds__(256)
void partition_edges(const int* __restrict__ rows,
                     const int* __restrict__ cols,
                     const float* __restrict__ vals,
                     int nnz, int K_i, int K_all,
                     int* __restrict__ cursor, uint2* __restrict__ pairs) {
    extern __shared__ int h[];   // K_all ints
    const int c0 = blockIdx.x * CHUNK;
    const int c1 = min(c0 + CHUNK, nnz);
    for (int t = threadIdx.x; t < K_all; t += blockDim.x) h[t] = 0;
    __syncthreads();
    // sweep A: local histogram
    for (int e = c0 + (int)threadIdx.x; e < c1; e += blockDim.x) {
        atomicAdd(&h[cols[e] >> 6], 1);
        atomicAdd(&h[K_i + (rows[e] >> 6)], 1);
    }
    __syncthreads();
    // claim: one global atomic per nonzero bucket; h[t] becomes global base
    for (int t = threadIdx.x; t < K_all; t += blockDim.x) {
        const int cnt = h[t];
        if (cnt) h[t] = atomicAdd(&cursor[t], cnt);
    }
    __syncthreads();
    // sweep B: scatter pairs into claimed (mostly sequential) segments
    for (int e = c0 + (int)threadIdx.x; e < c1; e += blockDim.x) {
        const int r = rows[e];
        const int c = cols[e];
        const unsigned vb = __float_as_uint(vals[e]);
        const int si = atomicAdd(&h[c >> 6], 1);            // item side: dest=c, nbr=r
        pairs[si] = make_uint2(((unsigned)(c & 63) << 17) | (unsigned)r, vb);
        const int su = atomicAdd(&h[K_i + (r >> 6)], 1);    // user side: dest=r, nbr=c
        pairs[su] = make_uint2(((unsigned)(r & 63) << 17) | (unsigned)c, vb);
    }
}

// ---------------- stage 4: split per-bucket LDS accumulate ----------------
// gridDim.x == K_all * SPLIT. Block (b, s) processes slice s of bucket b,
// accumulates partials for the bucket's 64 rows in LDS, then atomically
// merges nonzero elements into the (pre-zeroed) global output.
__global__ __launch_bounds__(256)
void bucket_accumulate_split(const float* __restrict__ user_emb,
                             const float* __restrict__ item_emb,
                             const uint2* __restrict__ pairs,
                             const int* __restrict__ base,
                             const int* __restrict__ counts,
                             int K_i, int n_users, int n_items,
                             float* __restrict__ user_out,
                             float* __restrict__ item_out) {
    __shared__ float acc[RB * DIM];   // 16 KiB
    const int b = blockIdx.x / SPLIT;
    const int s = blockIdx.x % SPLIT;
    const bool item_side = (b < K_i);
    const int bb = item_side ? b : (b - K_i);
    const int base_row = bb * RB;
    const int nrows_all = item_side ? n_items : n_users;
    const float* __restrict__ emb = item_side ? user_emb : item_emb;
    float* __restrict__ out = item_side ? item_out : user_out;

    for (int i = threadIdx.x; i < RB * DIM; i += blockDim.x) acc[i] = 0.f;
    __syncthreads();

    // this block's slice of the bucket
    const int bstart = base[b];
    const int btotal = counts[b];
    const int per_s  = (btotal + SPLIT - 1) / SPLIT;
    const int sstart = bstart + s * per_s;
    const int send   = min(sstart + per_s, bstart + btotal);

    const int lane = threadIdx.x & 63;
    const int wid  = threadIdx.x >> 6;
    const int nw   = blockDim.x >> 6;

    // wave-contiguous sub-slices
    const int total = max(send - sstart, 0);
    const int per_w = (total + nw - 1) / nw;
    const int ws    = sstart + wid * per_w;
    const int we    = min(ws + per_w, send);

    int e = ws;
    for (; e + 4 <= we; e += 4) {
        const uint2 p0 = pairs[e + 0];
        const uint2 p1 = pairs[e + 1];
        const uint2 p2 = pairs[e + 2];
        const uint2 p3 = pairs[e + 3];
        const float g0 = emb[(size_t)(p0.x & 0x1FFFFu) * DIM + lane];
        const float g1 = emb[(size_t)(p1.x & 0x1FFFFu) * DIM + lane];
        const float g2 = emb[(size_t)(p2.x & 0x1FFFFu) * DIM + lane];
        const float g3 = emb[(size_t)(p3.x & 0x1FFFFu) * DIM + lane];
        atomicAdd(&acc[((p0.x >> 17) << 6) + lane], __uint_as_float(p0.y) * g0);
        atomicAdd(&acc[((p1.x >> 17) << 6) + lane], __uint_as_float(p1.y) * g1);
        atomicAdd(&acc[((p2.x >> 17) << 6) + lane], __uint_as_float(p2.y) * g2);
        atomicAdd(&acc[((p3.x >> 17) << 6) + lane], __uint_as_float(p3.y) * g3);
    }
    for (; e < we; ++e) {
        const uint2 p = pairs[e];
        const float g = emb[(size_t)(p.x & 0x1FFFFu) * DIM + lane];
        atomicAdd(&acc[((p.x >> 17) << 6) + lane], __uint_as_float(p.y) * g);
    }
    __syncthreads();

    // merge partials; skip zeros (saves atomics on sparse/empty slices)
    const int nrows = min(RB, nrows_all - base_row);
    for (int i = threadIdx.x; i < nrows * DIM; i += blockDim.x) {
        const float v = acc[i];
        if (v != 0.f) atomicAdd(&out[(size_t)base_row * DIM + i], v);
    }
}

extern "C" void kernel_launch(void* const* d_in, const int* in_sizes, int n_in,
                              void* d_out, int out_size, void* d_ws, size_t ws_size,
                              hipStream_t stream) {
    const float* user_emb = (const float*)d_in[0];
    const float* item_emb = (const float*)d_in[1];
    const int*   rows     = (const int*)d_in[2];
    const int*   cols     = (const int*)d_in[3];
    const float* vals     = (const float*)d_in[4];

    const int nnz     = in_sizes[2];
    const int n_users = in_sizes[0] / DIM;
    const int n_items = in_sizes[1] / DIM;

    float* user_out = (float*)d_out;
    float* item_out = (float*)d_out + (size_t)in_sizes[0];

    const int K_i   = (n_items + RB - 1) / RB;
    const int K_u   = (n_users + RB - 1) / RB;
    const int K_all = K_i + K_u;

    // Workspace: counts | base | cursor (each padded) | pairs[2*nnz]
    const size_t Kpad      = ((size_t)K_all + 1023) & ~(size_t)1023;
    const size_t meta_ints = 3 * Kpad;
    const size_t pairs_off = (meta_ints * sizeof(int) + 127) & ~(size_t)127;
    const size_t need      = pairs_off + 2 * (size_t)nnz * sizeof(uint2);

    if (ws_size < need || n_users > 131072 || n_items > 131072) {
        hipMemsetAsync(d_out, 0, (size_t)out_size * sizeof(float), stream);
        lightgcn_scatter_atomic<<<2048, 256, 0, stream>>>(user_emb, item_emb, rows,
                                                          cols, vals, user_out,
                                                          item_out, nnz);
        return;
    }

    int* counts = (int*)d_ws;
    int* bases  = counts + Kpad;
    int* cursor = bases + Kpad;
    uint2* pairs = (uint2*)((char*)d_ws + pairs_off);

    hipMemsetAsync(counts, 0, (size_t)K_all * sizeof(int), stream);
    hipMemsetAsync(d_out, 0, (size_t)out_size * sizeof(float), stream);

    const size_t hist_bytes = (size_t)K_all * sizeof(int);
    count_hist<<<1024, 256, hist_bytes, stream>>>(rows, cols, nnz, K_i, K_all, counts);
    exscan_small<<<1, 1024, 0, stream>>>(counts, K_all, bases, cursor);

    const int part_blocks = (nnz + CHUNK - 1) / CHUNK;
    partition_edges<<<part_blocks, 256, hist_bytes, stream>>>(rows, cols, vals, nnz,
                                                              K_i, K_all, cursor, pairs);

    bucket_accumulate_split<<<K_all * SPLIT, 256, 0, stream>>>(
        user_emb, item_emb, pairs, bases, counts, K_i, n_users, n_items,
        user_out, item_out);
}

// Round 5
// 6375.196 us; speedup vs baseline: 1.1452x; 1.0780x over previous
//
#include <hip/hip_runtime.h>

// LightGCN conv, two-level sort + register accumulate:
//   to_bf16 (gather tables) -> count_hist -> exscan -> partition (16-row
//   buckets, block-aggregated claims) -> refine (per-bucket row sort in
//   LDS/registers, coalesced writeback, emits row offsets) ->
//   row_accumulate (one wave per output row, register acc, zero atomics).

constexpr int DIM    = 64;
constexpr int RB     = 16;        // rows per bucket
constexpr int SHIFT  = 17;        // bits for neighbor id (ids < 2^17)
constexpr unsigned NMASK = (1u << SHIFT) - 1;
constexpr int CHUNK  = 16384;     // edges per partition block
constexpr int CAP    = 3072;      // refine capacity (pairs per bucket)
constexpr int RITERS = CAP / 256; // register-staged iterations

// ---------------- fallback (round-1) atomic kernel ----------------
__global__ void lightgcn_scatter_atomic(const float* __restrict__ user_emb,
                                        const float* __restrict__ item_emb,
                                        const int* __restrict__ rows,
                                        const int* __restrict__ cols,
                                        const float* __restrict__ vals,
                                        float* __restrict__ user_out,
                                        float* __restrict__ item_out,
                                        int nnz) {
    const int lane   = threadIdx.x & 63;
    const int wave   = (blockIdx.x * blockDim.x + threadIdx.x) >> 6;
    const int nwaves = (gridDim.x * blockDim.x) >> 6;
    for (int e = wave; e < nnz; e += nwaves) {
        const int r = rows[e];
        const int c = cols[e];
        const float v = vals[e];
        atomicAdd(&user_out[(size_t)r * DIM + lane], v * item_emb[(size_t)c * DIM + lane]);
        atomicAdd(&item_out[(size_t)c * DIM + lane], v * user_emb[(size_t)r * DIM + lane]);
    }
}

// ---------------- bf16 table conversion (RNE) ----------------
__global__ void to_bf16(const float* __restrict__ a, int n, ushort* __restrict__ o) {
    int i = blockIdx.x * blockDim.x + threadIdx.x;
    const int s = gridDim.x * blockDim.x;
    for (; i < n; i += s) {
        const unsigned u = __float_as_uint(a[i]);
        o[i] = (ushort)((u + 0x7FFFu + ((u >> 16) & 1u)) >> 16);
    }
}

// ---------------- stage 1: bucket histogram (block-local LDS) ----------------
__global__ void count_hist(const int* __restrict__ rows,
                           const int* __restrict__ cols,
                           int nnz, int K_i, int K_all,
                           int* __restrict__ counts) {
    extern __shared__ int h[];   // K_all ints
    for (int t = threadIdx.x; t < K_all; t += blockDim.x) h[t] = 0;
    __syncthreads();
    int i = blockIdx.x * blockDim.x + threadIdx.x;
    const int stride = gridDim.x * blockDim.x;
    for (; i < nnz; i += stride) {
        atomicAdd(&h[cols[i] >> 4], 1);              // item bucket
        atomicAdd(&h[K_i + (rows[i] >> 4)], 1);      // user bucket
    }
    __syncthreads();
    for (int t = threadIdx.x; t < K_all; t += blockDim.x)
        if (h[t]) atomicAdd(&counts[t], h[t]);
}

// ---------------- stage 2: exclusive scan over K_all buckets (1 block) -------
__global__ void exscan_small(const int* __restrict__ counts, int n,
                             int* __restrict__ base, int* __restrict__ cursor) {
    __shared__ int s[1024];
    __shared__ int carry_s;
    if (threadIdx.x == 0) carry_s = 0;
    __syncthreads();
    for (int b0 = 0; b0 < n; b0 += 1024) {
        const int i = b0 + (int)threadIdx.x;
        const int x = (i < n) ? counts[i] : 0;
        s[threadIdx.x] = x;
        __syncthreads();
        for (int off = 1; off < 1024; off <<= 1) {
            const int t = (threadIdx.x >= (unsigned)off) ? s[threadIdx.x - off] : 0;
            __syncthreads();
            s[threadIdx.x] += t;
            __syncthreads();
        }
        const int ex = carry_s + s[threadIdx.x] - x;
        if (i < n) { base[i] = ex; cursor[i] = ex; }
        const int tot = s[1023];
        __syncthreads();
        if (threadIdx.x == 0) carry_s += tot;
        __syncthreads();
    }
}

// ---------------- stage 3: partition (block-aggregated slot claims) ----------
__global__ __launch_bounds__(256)
void partition_edges(const int* __restrict__ rows,
                     const int* __restrict__ cols,
                     const float* __restrict__ vals,
                     int nnz, int K_i, int K_all,
                     int* __restrict__ cursor, uint2* __restrict__ pairs) {
    extern __shared__ int h[];   // K_all ints
    const int c0 = blockIdx.x * CHUNK;
    const int c1 = min(c0 + CHUNK, nnz);
    for (int t = threadIdx.x; t < K_all; t += blockDim.x) h[t] = 0;
    __syncthreads();
    for (int e = c0 + (int)threadIdx.x; e < c1; e += blockDim.x) {
        atomicAdd(&h[cols[e] >> 4], 1);
        atomicAdd(&h[K_i + (rows[e] >> 4)], 1);
    }
    __syncthreads();
    for (int t = threadIdx.x; t < K_all; t += blockDim.x) {
        const int cnt = h[t];
        if (cnt) h[t] = atomicAdd(&cursor[t], cnt);
    }
    __syncthreads();
    for (int e = c0 + (int)threadIdx.x; e < c1; e += blockDim.x) {
        const int r = rows[e];
        const int c = cols[e];
        const unsigned vb = __float_as_uint(vals[e]);
        const int si = atomicAdd(&h[c >> 4], 1);           // item side: dest=c, nbr=r
        pairs[si] = make_uint2(((unsigned)(c & 15) << SHIFT) | (unsigned)r, vb);
        const int su = atomicAdd(&h[K_i + (r >> 4)], 1);   // user side: dest=r, nbr=c
        pairs[su] = make_uint2(((unsigned)(r & 15) << SHIFT) | (unsigned)c, vb);
    }
}

// ---------------- stage 4: per-bucket row sort (one block per bucket) --------
// Loads the bucket into registers, histograms rows, scans, scatters into LDS,
// writes back coalesced. Emits row_start (global offset) per row; -1 flags an
// oversized (unsorted) bucket -> accumulate falls back to filtering.
__global__ __launch_bounds__(256)
void refine_buckets(uint2* __restrict__ pairs,
                    const int* __restrict__ base,
                    const int* __restrict__ counts,
                    int K_i, int n_users, int n_items,
                    int* __restrict__ row_start) {   // item rows then user rows
    __shared__ uint2 stage[CAP];   // 24 KiB
    __shared__ int rbase[RB];
    __shared__ int rcur[RB];
    const int b  = blockIdx.x;
    const int s0 = base[b];
    const int n  = counts[b];
    const bool item_side = (b < K_i);
    const int row0 = (item_side ? b : b - K_i) * RB;
    const int nrows_all = item_side ? n_items : n_users;
    int* rs = row_start + (item_side ? 0 : n_items);

    if (n > CAP) {   // never expected; correctness fallback
        if (threadIdx.x < RB) {
            const int gr = row0 + (int)threadIdx.x;
            if (gr < nrows_all) rs[gr] = -1;
        }
        return;
    }

    if (threadIdx.x < RB) rcur[threadIdx.x] = 0;
    __syncthreads();

    uint2 v[RITERS];
    #pragma unroll
    for (int k = 0; k < RITERS; ++k) {
        const int i = (int)threadIdx.x + k * 256;
        if (i < n) {
            v[k] = pairs[s0 + i];
            atomicAdd(&rcur[v[k].x >> SHIFT], 1);
        }
    }
    __syncthreads();
    if (threadIdx.x == 0) {
        int run = 0;
        for (int j = 0; j < RB; ++j) {
            const int c = rcur[j];
            rbase[j] = run;
            rcur[j]  = run;
            run += c;
        }
    }
    __syncthreads();
    #pragma unroll
    for (int k = 0; k < RITERS; ++k) {
        const int i = (int)threadIdx.x + k * 256;
        if (i < n) {
            const int slot = atomicAdd(&rcur[v[k].x >> SHIFT], 1);
            stage[slot] = v[k];
        }
    }
    __syncthreads();
    for (int i = threadIdx.x; i < n; i += 256) pairs[s0 + i] = stage[i];
    if (threadIdx.x < RB) {
        const int gr = row0 + (int)threadIdx.x;
        if (gr < nrows_all) rs[gr] = s0 + rbase[threadIdx.x];
    }
}

// ---------------- stage 5: one wave per output row, register accumulate ------
template<bool BF16>
__global__ __launch_bounds__(256)
void row_accumulate(const void* __restrict__ tbl,       // neighbor table
                    const uint2* __restrict__ pairs,
                    const int* __restrict__ base,
                    const int* __restrict__ counts,
                    const int* __restrict__ row_start,  // this side's rows
                    int bucket0, int nrows,
                    float* __restrict__ out) {
    const int lane = threadIdx.x & 63;
    const int r = (int)((blockIdx.x * blockDim.x + threadIdx.x) >> 6);
    if (r >= nrows) return;

    const int b    = bucket0 + (r >> 4);
    const int bend = base[b] + counts[b];
    int st = row_start[r];
    int en;
    bool filter = false;
    if (st < 0) { st = base[b]; en = bend; filter = true; }
    else        { en = ((r & 15) == 15 || r + 1 == nrows) ? bend : row_start[r + 1]; }

    const ushort* tb = (const ushort*)tbl;
    const float*  tf = (const float*)tbl;
    float acc = 0.f;
    int e = st;

    if (!filter) {
        for (; e + 4 <= en; e += 4) {
            const uint2 p0 = pairs[e + 0];
            const uint2 p1 = pairs[e + 1];
            const uint2 p2 = pairs[e + 2];
            const uint2 p3 = pairs[e + 3];
            float g0, g1, g2, g3;
            if (BF16) {
                g0 = __uint_as_float((unsigned)tb[(size_t)(p0.x & NMASK) * DIM + lane] << 16);
                g1 = __uint_as_float((unsigned)tb[(size_t)(p1.x & NMASK) * DIM + lane] << 16);
                g2 = __uint_as_float((unsigned)tb[(size_t)(p2.x & NMASK) * DIM + lane] << 16);
                g3 = __uint_as_float((unsigned)tb[(size_t)(p3.x & NMASK) * DIM + lane] << 16);
            } else {
                g0 = tf[(size_t)(p0.x & NMASK) * DIM + lane];
                g1 = tf[(size_t)(p1.x & NMASK) * DIM + lane];
                g2 = tf[(size_t)(p2.x & NMASK) * DIM + lane];
                g3 = tf[(size_t)(p3.x & NMASK) * DIM + lane];
            }
            acc = fmaf(__uint_as_float(p0.y), g0, acc);
            acc = fmaf(__uint_as_float(p1.y), g1, acc);
            acc = fmaf(__uint_as_float(p2.y), g2, acc);
            acc = fmaf(__uint_as_float(p3.y), g3, acc);
        }
        for (; e < en; ++e) {
            const uint2 p = pairs[e];
            float g;
            if (BF16) g = __uint_as_float((unsigned)tb[(size_t)(p.x & NMASK) * DIM + lane] << 16);
            else      g = tf[(size_t)(p.x & NMASK) * DIM + lane];
            acc = fmaf(__uint_as_float(p.y), g, acc);
        }
    } else {
        const unsigned want = (unsigned)(r & 15);
        for (; e < en; ++e) {
            const uint2 p = pairs[e];
            if ((p.x >> SHIFT) == want) {
                float g;
                if (BF16) g = __uint_as_float((unsigned)tb[(size_t)(p.x & NMASK) * DIM + lane] << 16);
                else      g = tf[(size_t)(p.x & NMASK) * DIM + lane];
                acc = fmaf(__uint_as_float(p.y), g, acc);
            }
        }
    }
    out[(size_t)r * DIM + lane] = acc;
}

extern "C" void kernel_launch(void* const* d_in, const int* in_sizes, int n_in,
                              void* d_out, int out_size, void* d_ws, size_t ws_size,
                              hipStream_t stream) {
    const float* user_emb = (const float*)d_in[0];
    const float* item_emb = (const float*)d_in[1];
    const int*   rows     = (const int*)d_in[2];
    const int*   cols     = (const int*)d_in[3];
    const float* vals     = (const float*)d_in[4];

    const int nnz     = in_sizes[2];
    const int n_users = in_sizes[0] / DIM;
    const int n_items = in_sizes[1] / DIM;

    float* user_out = (float*)d_out;
    float* item_out = (float*)d_out + (size_t)in_sizes[0];

    const int K_i   = (n_items + RB - 1) / RB;
    const int K_u   = (n_users + RB - 1) / RB;
    const int K_all = K_i + K_u;

    // Workspace layout: counts|bases|cursor (Kpad each) | row_start | [bf16
    // tables] | pairs[2*nnz].
    const size_t Kpad       = ((size_t)K_all + 1023) & ~(size_t)1023;
    const size_t rows_total = (size_t)n_users + (size_t)n_items;
    const size_t meta_ints  = 3 * Kpad + ((rows_total + 63) & ~(size_t)63);
    size_t tbl_off = (meta_ints * sizeof(int) + 255) & ~(size_t)255;
    const size_t tbl_bytes  = rows_total * DIM * sizeof(ushort);
    const size_t pairs_bytes = 2 * (size_t)nnz * sizeof(uint2);
    const size_t pairs_off_bf16 = (tbl_off + tbl_bytes + 255) & ~(size_t)255;
    const size_t need_bf16 = pairs_off_bf16 + pairs_bytes;
    const size_t need_f32  = tbl_off + pairs_bytes;

    if (n_users > (1 << SHIFT) || n_items > (1 << SHIFT) || ws_size < need_f32) {
        hipMemsetAsync(d_out, 0, (size_t)out_size * sizeof(float), stream);
        lightgcn_scatter_atomic<<<2048, 256, 0, stream>>>(user_emb, item_emb, rows,
                                                          cols, vals, user_out,
                                                          item_out, nnz);
        return;
    }

    const bool use_bf16 = (ws_size >= need_bf16);

    int* counts    = (int*)d_ws;
    int* bases     = counts + Kpad;
    int* cursor    = bases + Kpad;
    int* row_start = cursor + Kpad;            // item rows [0,n_items), then user
    ushort* tblu   = (ushort*)((char*)d_ws + tbl_off);
    ushort* tbli   = tblu + (size_t)n_users * DIM;
    uint2* pairs   = (uint2*)((char*)d_ws + (use_bf16 ? pairs_off_bf16 : tbl_off));

    if (use_bf16) {
        to_bf16<<<512, 256, 0, stream>>>(user_emb, n_users * DIM, tblu);
        to_bf16<<<512, 256, 0, stream>>>(item_emb, n_items * DIM, tbli);
    }
    hipMemsetAsync(counts, 0, (size_t)K_all * sizeof(int), stream);

    const size_t hist_bytes = (size_t)K_all * sizeof(int);
    count_hist<<<512, 256, hist_bytes, stream>>>(rows, cols, nnz, K_i, K_all, counts);
    exscan_small<<<1, 1024, 0, stream>>>(counts, K_all, bases, cursor);
    partition_edges<<<(nnz + CHUNK - 1) / CHUNK, 256, hist_bytes, stream>>>(
        rows, cols, vals, nnz, K_i, K_all, cursor, pairs);
    refine_buckets<<<K_all, 256, 0, stream>>>(pairs, bases, counts, K_i,
                                              n_users, n_items, row_start);

    const int blk_i = (int)(((size_t)n_items * 64 + 255) / 256);
    const int blk_u = (int)(((size_t)n_users * 64 + 255) / 256);
    if (use_bf16) {
        row_accumulate<true><<<blk_i, 256, 0, stream>>>(tblu, pairs, bases, counts,
                                                        row_start, 0, n_items, item_out);
        row_accumulate<true><<<blk_u, 256, 0, stream>>>(tbli, pairs, bases, counts,
                                                        row_start + n_items, K_i,
                                                        n_users, user_out);
    } else {
        row_accumulate<false><<<blk_i, 256, 0, stream>>>(user_emb, pairs, bases, counts,
                                                         row_start, 0, n_items, item_out);
        row_accumulate<false><<<blk_u, 256, 0, stream>>>(item_emb, pairs, bases, counts,
                                                         row_start + n_items, K_i,
                                                         n_users, user_out);
    }
}

// Round 6
// 1230.283 us; speedup vs baseline: 5.9345x; 5.1819x over previous
//
#include <hip/hip_runtime.h>

// LightGCN conv, two-level sort + register accumulate:
//   to_bf16 (gather tables) -> count_hist -> exscan -> partition (16-row
//   buckets, block-aggregated claims) -> refine (per-bucket row sort in
//   LDS/registers, coalesced writeback, emits row offsets) ->
//   row_accumulate (one wave per output row, register acc, zero atomics).
// R6 fix: CAP 3072 -> 4096. Item buckets average 3200 pairs (16 rows x deg
// 200); at CAP=3072 refine flagged ~all item buckets oversized and the
// accumulate took the 16x-redundant filter path (the 5.5 ms dispatch).

constexpr int DIM    = 64;
constexpr int RB     = 16;        // rows per bucket
constexpr int SHIFT  = 17;        // bits for neighbor id (ids < 2^17)
constexpr unsigned NMASK = (1u << SHIFT) - 1;
constexpr int CHUNK  = 16384;     // edges per partition block
constexpr int CAP    = 4096;      // refine capacity (pairs per bucket)
constexpr int RITERS = CAP / 256; // register-staged iterations

// ---------------- fallback (round-1) atomic kernel ----------------
__global__ void lightgcn_scatter_atomic(const float* __restrict__ user_emb,
                                        const float* __restrict__ item_emb,
                                        const int* __restrict__ rows,
                                        const int* __restrict__ cols,
                                        const float* __restrict__ vals,
                                        float* __restrict__ user_out,
                                        float* __restrict__ item_out,
                                        int nnz) {
    const int lane   = threadIdx.x & 63;
    const int wave   = (blockIdx.x * blockDim.x + threadIdx.x) >> 6;
    const int nwaves = (gridDim.x * blockDim.x) >> 6;
    for (int e = wave; e < nnz; e += nwaves) {
        const int r = rows[e];
        const int c = cols[e];
        const float v = vals[e];
        atomicAdd(&user_out[(size_t)r * DIM + lane], v * item_emb[(size_t)c * DIM + lane]);
        atomicAdd(&item_out[(size_t)c * DIM + lane], v * user_emb[(size_t)r * DIM + lane]);
    }
}

// ---------------- bf16 table conversion (RNE) ----------------
__global__ void to_bf16(const float* __restrict__ a, int n, ushort* __restrict__ o) {
    int i = blockIdx.x * blockDim.x + threadIdx.x;
    const int s = gridDim.x * blockDim.x;
    for (; i < n; i += s) {
        const unsigned u = __float_as_uint(a[i]);
        o[i] = (ushort)((u + 0x7FFFu + ((u >> 16) & 1u)) >> 16);
    }
}

// ---------------- stage 1: bucket histogram (block-local LDS) ----------------
__global__ void count_hist(const int* __restrict__ rows,
                           const int* __restrict__ cols,
                           int nnz, int K_i, int K_all,
                           int* __restrict__ counts) {
    extern __shared__ int h[];   // K_all ints
    for (int t = threadIdx.x; t < K_all; t += blockDim.x) h[t] = 0;
    __syncthreads();
    int i = blockIdx.x * blockDim.x + threadIdx.x;
    const int stride = gridDim.x * blockDim.x;
    for (; i < nnz; i += stride) {
        atomicAdd(&h[cols[i] >> 4], 1);              // item bucket
        atomicAdd(&h[K_i + (rows[i] >> 4)], 1);      // user bucket
    }
    __syncthreads();
    for (int t = threadIdx.x; t < K_all; t += blockDim.x)
        if (h[t]) atomicAdd(&counts[t], h[t]);
}

// ---------------- stage 2: exclusive scan over K_all buckets (1 block) -------
__global__ void exscan_small(const int* __restrict__ counts, int n,
                             int* __restrict__ base, int* __restrict__ cursor) {
    __shared__ int s[1024];
    __shared__ int carry_s;
    if (threadIdx.x == 0) carry_s = 0;
    __syncthreads();
    for (int b0 = 0; b0 < n; b0 += 1024) {
        const int i = b0 + (int)threadIdx.x;
        const int x = (i < n) ? counts[i] : 0;
        s[threadIdx.x] = x;
        __syncthreads();
        for (int off = 1; off < 1024; off <<= 1) {
            const int t = (threadIdx.x >= (unsigned)off) ? s[threadIdx.x - off] : 0;
            __syncthreads();
            s[threadIdx.x] += t;
            __syncthreads();
        }
        const int ex = carry_s + s[threadIdx.x] - x;
        if (i < n) { base[i] = ex; cursor[i] = ex; }
        const int tot = s[1023];
        __syncthreads();
        if (threadIdx.x == 0) carry_s += tot;
        __syncthreads();
    }
}

// ---------------- stage 3: partition (block-aggregated slot claims) ----------
__global__ __launch_bounds__(256)
void partition_edges(const int* __restrict__ rows,
                     const int* __restrict__ cols,
                     const float* __restrict__ vals,
                     int nnz, int K_i, int K_all,
                     int* __restrict__ cursor, uint2* __restrict__ pairs) {
    extern __shared__ int h[];   // K_all ints
    const int c0 = blockIdx.x * CHUNK;
    const int c1 = min(c0 + CHUNK, nnz);
    for (int t = threadIdx.x; t < K_all; t += blockDim.x) h[t] = 0;
    __syncthreads();
    for (int e = c0 + (int)threadIdx.x; e < c1; e += blockDim.x) {
        atomicAdd(&h[cols[e] >> 4], 1);
        atomicAdd(&h[K_i + (rows[e] >> 4)], 1);
    }
    __syncthreads();
    for (int t = threadIdx.x; t < K_all; t += blockDim.x) {
        const int cnt = h[t];
        if (cnt) h[t] = atomicAdd(&cursor[t], cnt);
    }
    __syncthreads();
    for (int e = c0 + (int)threadIdx.x; e < c1; e += blockDim.x) {
        const int r = rows[e];
        const int c = cols[e];
        const unsigned vb = __float_as_uint(vals[e]);
        const int si = atomicAdd(&h[c >> 4], 1);           // item side: dest=c, nbr=r
        pairs[si] = make_uint2(((unsigned)(c & 15) << SHIFT) | (unsigned)r, vb);
        const int su = atomicAdd(&h[K_i + (r >> 4)], 1);   // user side: dest=r, nbr=c
        pairs[su] = make_uint2(((unsigned)(r & 15) << SHIFT) | (unsigned)c, vb);
    }
}

// ---------------- stage 4: per-bucket row sort (one block per bucket) --------
// Loads the bucket into registers, histograms rows, scans, scatters into LDS,
// writes back coalesced. Emits row_start (global offset) per row; -1 flags an
// oversized (unsorted) bucket -> accumulate falls back to filtering.
__global__ __launch_bounds__(256)
void refine_buckets(uint2* __restrict__ pairs,
                    const int* __restrict__ base,
                    const int* __restrict__ counts,
                    int K_i, int n_users, int n_items,
                    int* __restrict__ row_start) {   // item rows then user rows
    __shared__ uint2 stage[CAP];   // 32 KiB
    __shared__ int rbase[RB];
    __shared__ int rcur[RB];
    const int b  = blockIdx.x;
    const int s0 = base[b];
    const int n  = counts[b];
    const bool item_side = (b < K_i);
    const int row0 = (item_side ? b : b - K_i) * RB;
    const int nrows_all = item_side ? n_items : n_users;
    int* rs = row_start + (item_side ? 0 : n_items);

    if (n > CAP) {   // never expected; correctness fallback
        if (threadIdx.x < RB) {
            const int gr = row0 + (int)threadIdx.x;
            if (gr < nrows_all) rs[gr] = -1;
        }
        return;
    }

    if (threadIdx.x < RB) rcur[threadIdx.x] = 0;
    __syncthreads();

    uint2 v[RITERS];
    #pragma unroll
    for (int k = 0; k < RITERS; ++k) {
        const int i = (int)threadIdx.x + k * 256;
        if (i < n) {
            v[k] = pairs[s0 + i];
            atomicAdd(&rcur[v[k].x >> SHIFT], 1);
        }
    }
    __syncthreads();
    if (threadIdx.x == 0) {
        int run = 0;
        for (int j = 0; j < RB; ++j) {
            const int c = rcur[j];
            rbase[j] = run;
            rcur[j]  = run;
            run += c;
        }
    }
    __syncthreads();
    #pragma unroll
    for (int k = 0; k < RITERS; ++k) {
        const int i = (int)threadIdx.x + k * 256;
        if (i < n) {
            const int slot = atomicAdd(&rcur[v[k].x >> SHIFT], 1);
            stage[slot] = v[k];
        }
    }
    __syncthreads();
    for (int i = threadIdx.x; i < n; i += 256) pairs[s0 + i] = stage[i];
    if (threadIdx.x < RB) {
        const int gr = row0 + (int)threadIdx.x;
        if (gr < nrows_all) rs[gr] = s0 + rbase[threadIdx.x];
    }
}

// ---------------- stage 5: one wave per output row, register accumulate ------
template<bool BF16>
__global__ __launch_bounds__(256)
void row_accumulate(const void* __restrict__ tbl,       // neighbor table
                    const uint2* __restrict__ pairs,
                    const int* __restrict__ base,
                    const int* __restrict__ counts,
                    const int* __restrict__ row_start,  // this side's rows
                    int bucket0, int nrows,
                    float* __restrict__ out) {
    const int lane = threadIdx.x & 63;
    const int r = (int)((blockIdx.x * blockDim.x + threadIdx.x) >> 6);
    if (r >= nrows) return;

    const int b    = bucket0 + (r >> 4);
    const int bend = base[b] + counts[b];
    int st = row_start[r];
    int en;
    bool filter = false;
    if (st < 0) { st = base[b]; en = bend; filter = true; }
    else        { en = ((r & 15) == 15 || r + 1 == nrows) ? bend : row_start[r + 1]; }

    const ushort* tb = (const ushort*)tbl;
    const float*  tf = (const float*)tbl;
    float acc = 0.f;
    int e = st;

    if (!filter) {
        for (; e + 4 <= en; e += 4) {
            const uint2 p0 = pairs[e + 0];
            const uint2 p1 = pairs[e + 1];
            const uint2 p2 = pairs[e + 2];
            const uint2 p3 = pairs[e + 3];
            float g0, g1, g2, g3;
            if (BF16) {
                g0 = __uint_as_float((unsigned)tb[(size_t)(p0.x & NMASK) * DIM + lane] << 16);
                g1 = __uint_as_float((unsigned)tb[(size_t)(p1.x & NMASK) * DIM + lane] << 16);
                g2 = __uint_as_float((unsigned)tb[(size_t)(p2.x & NMASK) * DIM + lane] << 16);
                g3 = __uint_as_float((unsigned)tb[(size_t)(p3.x & NMASK) * DIM + lane] << 16);
            } else {
                g0 = tf[(size_t)(p0.x & NMASK) * DIM + lane];
                g1 = tf[(size_t)(p1.x & NMASK) * DIM + lane];
                g2 = tf[(size_t)(p2.x & NMASK) * DIM + lane];
                g3 = tf[(size_t)(p3.x & NMASK) * DIM + lane];
            }
            acc = fmaf(__uint_as_float(p0.y), g0, acc);
            acc = fmaf(__uint_as_float(p1.y), g1, acc);
            acc = fmaf(__uint_as_float(p2.y), g2, acc);
            acc = fmaf(__uint_as_float(p3.y), g3, acc);
        }
        for (; e < en; ++e) {
            const uint2 p = pairs[e];
            float g;
            if (BF16) g = __uint_as_float((unsigned)tb[(size_t)(p.x & NMASK) * DIM + lane] << 16);
            else      g = tf[(size_t)(p.x & NMASK) * DIM + lane];
            acc = fmaf(__uint_as_float(p.y), g, acc);
        }
    } else {
        const unsigned want = (unsigned)(r & 15);
        for (; e < en; ++e) {
            const uint2 p = pairs[e];
            if ((p.x >> SHIFT) == want) {
                float g;
                if (BF16) g = __uint_as_float((unsigned)tb[(size_t)(p.x & NMASK) * DIM + lane] << 16);
                else      g = tf[(size_t)(p.x & NMASK) * DIM + lane];
                acc = fmaf(__uint_as_float(p.y), g, acc);
            }
        }
    }
    out[(size_t)r * DIM + lane] = acc;
}

extern "C" void kernel_launch(void* const* d_in, const int* in_sizes, int n_in,
                              void* d_out, int out_size, void* d_ws, size_t ws_size,
                              hipStream_t stream) {
    const float* user_emb = (const float*)d_in[0];
    const float* item_emb = (const float*)d_in[1];
    const int*   rows     = (const int*)d_in[2];
    const int*   cols     = (const int*)d_in[3];
    const float* vals     = (const float*)d_in[4];

    const int nnz     = in_sizes[2];
    const int n_users = in_sizes[0] / DIM;
    const int n_items = in_sizes[1] / DIM;

    float* user_out = (float*)d_out;
    float* item_out = (float*)d_out + (size_t)in_sizes[0];

    const int K_i   = (n_items + RB - 1) / RB;
    const int K_u   = (n_users + RB - 1) / RB;
    const int K_all = K_i + K_u;

    // Workspace layout: counts|bases|cursor (Kpad each) | row_start | [bf16
    // tables] | pairs[2*nnz].
    const size_t Kpad       = ((size_t)K_all + 1023) & ~(size_t)1023;
    const size_t rows_total = (size_t)n_users + (size_t)n_items;
    const size_t meta_ints  = 3 * Kpad + ((rows_total + 63) & ~(size_t)63);
    size_t tbl_off = (meta_ints * sizeof(int) + 255) & ~(size_t)255;
    const size_t tbl_bytes  = rows_total * DIM * sizeof(ushort);
    const size_t pairs_bytes = 2 * (size_t)nnz * sizeof(uint2);
    const size_t pairs_off_bf16 = (tbl_off + tbl_bytes + 255) & ~(size_t)255;
    const size_t need_bf16 = pairs_off_bf16 + pairs_bytes;
    const size_t need_f32  = tbl_off + pairs_bytes;

    if (n_users > (1 << SHIFT) || n_items > (1 << SHIFT) || ws_size < need_f32) {
        hipMemsetAsync(d_out, 0, (size_t)out_size * sizeof(float), stream);
        lightgcn_scatter_atomic<<<2048, 256, 0, stream>>>(user_emb, item_emb, rows,
                                                          cols, vals, user_out,
                                                          item_out, nnz);
        return;
    }

    const bool use_bf16 = (ws_size >= need_bf16);

    int* counts    = (int*)d_ws;
    int* bases     = counts + Kpad;
    int* cursor    = bases + Kpad;
    int* row_start = cursor + Kpad;            // item rows [0,n_items), then user
    ushort* tblu   = (ushort*)((char*)d_ws + tbl_off);
    ushort* tbli   = tblu + (size_t)n_users * DIM;
    uint2* pairs   = (uint2*)((char*)d_ws + (use_bf16 ? pairs_off_bf16 : tbl_off));

    if (use_bf16) {
        to_bf16<<<512, 256, 0, stream>>>(user_emb, n_users * DIM, tblu);
        to_bf16<<<512, 256, 0, stream>>>(item_emb, n_items * DIM, tbli);
    }
    hipMemsetAsync(counts, 0, (size_t)K_all * sizeof(int), stream);

    const size_t hist_bytes = (size_t)K_all * sizeof(int);
    count_hist<<<512, 256, hist_bytes, stream>>>(rows, cols, nnz, K_i, K_all, counts);
    exscan_small<<<1, 1024, 0, stream>>>(counts, K_all, bases, cursor);
    partition_edges<<<(nnz + CHUNK - 1) / CHUNK, 256, hist_bytes, stream>>>(
        rows, cols, vals, nnz, K_i, K_all, cursor, pairs);
    refine_buckets<<<K_all, 256, 0, stream>>>(pairs, bases, counts, K_i,
                                              n_users, n_items, row_start);

    const int blk_i = (int)(((size_t)n_items * 64 + 255) / 256);
    const int blk_u = (int)(((size_t)n_users * 64 + 255) / 256);
    if (use_bf16) {
        row_accumulate<true><<<blk_i, 256, 0, stream>>>(tblu, pairs, bases, counts,
                                                        row_start, 0, n_items, item_out);
        row_accumulate<true><<<blk_u, 256, 0, stream>>>(tbli, pairs, bases, counts,
                                                        row_start + n_items, K_i,
                                                        n_users, user_out);
    } else {
        row_accumulate<false><<<blk_i, 256, 0, stream>>>(user_emb, pairs, bases, counts,
                                                         row_start, 0, n_items, item_out);
        row_accumulate<false><<<blk_u, 256, 0, stream>>>(item_emb, pairs, bases, counts,
                                                         row_start + n_items, K_i,
                                                         n_users, user_out);
    }
}

// Round 8
// 1146.741 us; speedup vs baseline: 6.3668x; 1.0729x over previous
//
#include <hip/hip_runtime.h>

// LightGCN conv, coarse-sort + staged refine + register accumulate:
//   to_bf16 -> count_hist (64-row buckets) -> exscan -> partition (64-row
//   buckets, block-aggregated claims) -> refine (bucket register-resident,
//   64 LDS row cursors, 4x 16-row groups staged through LDS, CONTIGUOUS
//   writeback, out-of-place into pairsB when ws allows) ->
//   row_accumulate (one wave per output row, register acc, zero atomics).
// R8: R7's refine scattered 8B stores in place and a timed replay diverged
// (one pair lost/dup). Writeback is now contiguous via LDS stage (the R6
// pattern that passed), and out-of-place when ws_size permits.

constexpr int DIM    = 64;
constexpr int RB     = 64;        // rows per bucket
constexpr int GROUPS = 4;         // staged sub-passes per bucket
constexpr int GR     = RB / GROUPS;           // 16 rows per group
constexpr int SHIFT  = 17;        // bits for neighbor id (ids < 2^17)
constexpr unsigned NMASK = (1u << SHIFT) - 1;
constexpr int CHUNK  = 16384;     // edges per partition block
constexpr int RTHREADS = 1024;    // refine block size
constexpr int RITERS   = 14;      // pairs per refine thread
constexpr int CAP      = RTHREADS * RITERS;   // 14336 pairs per bucket max
constexpr int CAP_G    = 5120;    // per-group LDS stage capacity (40 KB)

// ---------------- fallback (round-1) atomic kernel ----------------
__global__ void lightgcn_scatter_atomic(const float* __restrict__ user_emb,
                                        const float* __restrict__ item_emb,
                                        const int* __restrict__ rows,
                                        const int* __restrict__ cols,
                                        const float* __restrict__ vals,
                                        float* __restrict__ user_out,
                                        float* __restrict__ item_out,
                                        int nnz) {
    const int lane   = threadIdx.x & 63;
    const int wave   = (blockIdx.x * blockDim.x + threadIdx.x) >> 6;
    const int nwaves = (gridDim.x * blockDim.x) >> 6;
    for (int e = wave; e < nnz; e += nwaves) {
        const int r = rows[e];
        const int c = cols[e];
        const float v = vals[e];
        atomicAdd(&user_out[(size_t)r * DIM + lane], v * item_emb[(size_t)c * DIM + lane]);
        atomicAdd(&item_out[(size_t)c * DIM + lane], v * user_emb[(size_t)r * DIM + lane]);
    }
}

// ---------------- bf16 table conversion (RNE) ----------------
__global__ void to_bf16(const float* __restrict__ a, int n, ushort* __restrict__ o) {
    int i = blockIdx.x * blockDim.x + threadIdx.x;
    const int s = gridDim.x * blockDim.x;
    for (; i < n; i += s) {
        const unsigned u = __float_as_uint(a[i]);
        o[i] = (ushort)((u + 0x7FFFu + ((u >> 16) & 1u)) >> 16);
    }
}

// ---------------- stage 1: bucket histogram (block-local LDS) ----------------
__global__ void count_hist(const int* __restrict__ rows,
                           const int* __restrict__ cols,
                           int nnz, int K_i, int K_all,
                           int* __restrict__ counts) {
    extern __shared__ int h[];   // K_all ints (~9.4 KB)
    for (int t = threadIdx.x; t < K_all; t += blockDim.x) h[t] = 0;
    __syncthreads();
    int i = blockIdx.x * blockDim.x + threadIdx.x;
    const int stride = gridDim.x * blockDim.x;
    for (; i < nnz; i += stride) {
        atomicAdd(&h[cols[i] >> 6], 1);              // item bucket
        atomicAdd(&h[K_i + (rows[i] >> 6)], 1);      // user bucket
    }
    __syncthreads();
    for (int t = threadIdx.x; t < K_all; t += blockDim.x)
        if (h[t]) atomicAdd(&counts[t], h[t]);
}

// ---------------- stage 2: exclusive scan over K_all buckets (1 block) -------
__global__ void exscan_small(const int* __restrict__ counts, int n,
                             int* __restrict__ base, int* __restrict__ cursor) {
    __shared__ int s[1024];
    __shared__ int carry_s;
    if (threadIdx.x == 0) carry_s = 0;
    __syncthreads();
    for (int b0 = 0; b0 < n; b0 += 1024) {
        const int i = b0 + (int)threadIdx.x;
        const int x = (i < n) ? counts[i] : 0;
        s[threadIdx.x] = x;
        __syncthreads();
        for (int off = 1; off < 1024; off <<= 1) {
            const int t = (threadIdx.x >= (unsigned)off) ? s[threadIdx.x - off] : 0;
            __syncthreads();
            s[threadIdx.x] += t;
            __syncthreads();
        }
        const int ex = carry_s + s[threadIdx.x] - x;
        if (i < n) { base[i] = ex; cursor[i] = ex; }
        const int tot = s[1023];
        __syncthreads();
        if (threadIdx.x == 0) carry_s += tot;
        __syncthreads();
    }
}

// ---------------- stage 3: partition (block-aggregated slot claims) ----------
__global__ __launch_bounds__(256)
void partition_edges(const int* __restrict__ rows,
                     const int* __restrict__ cols,
                     const float* __restrict__ vals,
                     int nnz, int K_i, int K_all,
                     int* __restrict__ cursor, uint2* __restrict__ pairs) {
    extern __shared__ int h[];   // K_all ints
    const int c0 = blockIdx.x * CHUNK;
    const int c1 = min(c0 + CHUNK, nnz);
    for (int t = threadIdx.x; t < K_all; t += blockDim.x) h[t] = 0;
    __syncthreads();
    for (int e = c0 + (int)threadIdx.x; e < c1; e += blockDim.x) {
        atomicAdd(&h[cols[e] >> 6], 1);
        atomicAdd(&h[K_i + (rows[e] >> 6)], 1);
    }
    __syncthreads();
    for (int t = threadIdx.x; t < K_all; t += blockDim.x) {
        const int cnt = h[t];
        if (cnt) h[t] = atomicAdd(&cursor[t], cnt);
    }
    __syncthreads();
    for (int e = c0 + (int)threadIdx.x; e < c1; e += blockDim.x) {
        const int r = rows[e];
        const int c = cols[e];
        const unsigned vb = __float_as_uint(vals[e]);
        const int si = atomicAdd(&h[c >> 6], 1);           // item side: dest=c, nbr=r
        pairs[si] = make_uint2(((unsigned)(c & 63) << SHIFT) | (unsigned)r, vb);
        const int su = atomicAdd(&h[K_i + (r >> 6)], 1);   // user side: dest=r, nbr=c
        pairs[su] = make_uint2(((unsigned)(r & 63) << SHIFT) | (unsigned)c, vb);
    }
}

// ---------------- stage 4: per-bucket row sort, staged writeback -------------
// Bucket (<=14336 pairs) register-resident; 64 LDS row counters; serial scan;
// then 4 sub-passes: group p's pairs claim slots and stage in LDS, followed by
// a CONTIGUOUS global writeback. dst may be a separate buffer (out-of-place,
// preferred) or equal src (in-place; later sub-passes only read registers).
__global__ __launch_bounds__(RTHREADS)
void refine_buckets(const uint2* __restrict__ src,
                    uint2* __restrict__ dst,
                    const int* __restrict__ base,
                    const int* __restrict__ counts,
                    int K_i, int n_users, int n_items,
                    int* __restrict__ row_start,   // item rows then user rows
                    int inplace) {
    __shared__ uint2 stage[CAP_G];    // 40 KiB
    __shared__ int rbase[RB + 1];
    __shared__ int rcur[RB];
    __shared__ int bad;
    const int b  = blockIdx.x;
    const int s0 = base[b];
    const int n  = counts[b];
    const bool item_side = (b < K_i);
    const int row0 = (item_side ? b : b - K_i) * RB;
    const int nrows_all = item_side ? n_items : n_users;
    int* rs = row_start + (item_side ? 0 : n_items);
    const int tid = threadIdx.x;

    if (n > CAP) {   // >13 sigma out; correctness fallback only
        if (!inplace) for (int i = tid; i < n; i += RTHREADS) dst[s0 + i] = src[s0 + i];
        if (tid < RB) {
            const int gr = row0 + tid;
            if (gr < nrows_all) rs[gr] = -1;
        }
        return;
    }

    if (tid < RB) rcur[tid] = 0;
    if (tid == 0) bad = 0;
    __syncthreads();

    uint2 v[RITERS];
    #pragma unroll
    for (int k = 0; k < RITERS; ++k) {
        const int i = tid + k * RTHREADS;
        if (i < n) {
            v[k] = src[s0 + i];
            atomicAdd(&rcur[v[k].x >> SHIFT], 1);
        }
    }
    __threadfence_block();   // insurance: drain before anyone passes the barrier
    __syncthreads();

    if (tid == 0) {
        int run = 0;
        for (int j = 0; j < RB; ++j) {
            const int c = rcur[j];
            rbase[j] = run;
            rcur[j]  = run;
            run += c;
        }
        rbase[RB] = run;
        for (int p = 0; p < GROUPS; ++p)
            if (rbase[(p + 1) * GR] - rbase[p * GR] > CAP_G) bad = 1;
    }
    __syncthreads();

    if (bad) {   // some 16-row group exceeds the stage; leave bucket unsorted
        if (!inplace) for (int i = tid; i < n; i += RTHREADS) dst[s0 + i] = src[s0 + i];
        if (tid < RB) {
            const int gr = row0 + tid;
            if (gr < nrows_all) rs[gr] = -1;
        }
        return;
    }

    for (int p = 0; p < GROUPS; ++p) {
        const int gstart = rbase[p * GR];
        const int gend   = rbase[(p + 1) * GR];
        #pragma unroll
        for (int k = 0; k < RITERS; ++k) {
            const int i = tid + k * RTHREADS;
            if (i < n) {
                const int row = (int)(v[k].x >> SHIFT);
                if ((row >> 4) == p) {
                    const int slot = atomicAdd(&rcur[row], 1);
                    stage[slot - gstart] = v[k];
                }
            }
        }
        __syncthreads();
        for (int i = tid; i < gend - gstart; i += RTHREADS)
            dst[s0 + gstart + i] = stage[i];
        __syncthreads();
    }

    if (tid < RB) {
        const int gr = row0 + tid;
        if (gr < nrows_all) rs[gr] = s0 + rbase[tid];
    }
}

// ---------------- stage 5: one wave per output row, register accumulate ------
__global__ __launch_bounds__(256)
void row_accumulate(const ushort* __restrict__ tbl,     // bf16 neighbor table
                    const uint2* __restrict__ pairs,
                    const int* __restrict__ base,
                    const int* __restrict__ counts,
                    const int* __restrict__ row_start,  // this side's rows
                    int bucket0, int nrows,
                    float* __restrict__ out) {
    const int lane = threadIdx.x & 63;
    const int r = (int)((blockIdx.x * blockDim.x + threadIdx.x) >> 6);
    if (r >= nrows) return;

    const int b    = bucket0 + (r >> 6);
    const int bend = base[b] + counts[b];
    int st = row_start[r];
    int en;
    bool filter = false;
    if (st < 0) { st = base[b]; en = bend; filter = true; }
    else        { en = ((r & 63) == 63 || r + 1 == nrows) ? bend : row_start[r + 1]; }

    float acc = 0.f;
    int e = st;

    if (!filter) {
        for (; e + 4 <= en; e += 4) {
            const uint2 p0 = pairs[e + 0];
            const uint2 p1 = pairs[e + 1];
            const uint2 p2 = pairs[e + 2];
            const uint2 p3 = pairs[e + 3];
            const float g0 = __uint_as_float((unsigned)tbl[(size_t)(p0.x & NMASK) * DIM + lane] << 16);
            const float g1 = __uint_as_float((unsigned)tbl[(size_t)(p1.x & NMASK) * DIM + lane] << 16);
            const float g2 = __uint_as_float((unsigned)tbl[(size_t)(p2.x & NMASK) * DIM + lane] << 16);
            const float g3 = __uint_as_float((unsigned)tbl[(size_t)(p3.x & NMASK) * DIM + lane] << 16);
            acc = fmaf(__uint_as_float(p0.y), g0, acc);
            acc = fmaf(__uint_as_float(p1.y), g1, acc);
            acc = fmaf(__uint_as_float(p2.y), g2, acc);
            acc = fmaf(__uint_as_float(p3.y), g3, acc);
        }
        for (; e < en; ++e) {
            const uint2 p = pairs[e];
            const float g = __uint_as_float((unsigned)tbl[(size_t)(p.x & NMASK) * DIM + lane] << 16);
            acc = fmaf(__uint_as_float(p.y), g, acc);
        }
    } else {
        const unsigned want = (unsigned)(r & 63);
        for (; e < en; ++e) {
            const uint2 p = pairs[e];
            if ((p.x >> SHIFT) == want) {
                const float g = __uint_as_float((unsigned)tbl[(size_t)(p.x & NMASK) * DIM + lane] << 16);
                acc = fmaf(__uint_as_float(p.y), g, acc);
            }
        }
    }
    out[(size_t)r * DIM + lane] = acc;
}

extern "C" void kernel_launch(void* const* d_in, const int* in_sizes, int n_in,
                              void* d_out, int out_size, void* d_ws, size_t ws_size,
                              hipStream_t stream) {
    const float* user_emb = (const float*)d_in[0];
    const float* item_emb = (const float*)d_in[1];
    const int*   rows     = (const int*)d_in[2];
    const int*   cols     = (const int*)d_in[3];
    const float* vals     = (const float*)d_in[4];

    const int nnz     = in_sizes[2];
    const int n_users = in_sizes[0] / DIM;
    const int n_items = in_sizes[1] / DIM;

    float* user_out = (float*)d_out;
    float* item_out = (float*)d_out + (size_t)in_sizes[0];

    const int K_i   = (n_items + RB - 1) / RB;
    const int K_u   = (n_users + RB - 1) / RB;
    const int K_all = K_i + K_u;

    // Workspace: counts|bases|cursor (Kpad each) | row_start | bf16 tables |
    // pairsA | [pairsB].
    const size_t Kpad       = ((size_t)K_all + 1023) & ~(size_t)1023;
    const size_t rows_total = (size_t)n_users + (size_t)n_items;
    const size_t meta_ints  = 3 * Kpad + ((rows_total + 63) & ~(size_t)63);
    const size_t tbl_off    = (meta_ints * sizeof(int) + 255) & ~(size_t)255;
    const size_t tbl_bytes  = rows_total * DIM * sizeof(ushort);
    const size_t pairs_bytes = 2 * (size_t)nnz * sizeof(uint2);
    const size_t pairsA_off = (tbl_off + tbl_bytes + 255) & ~(size_t)255;
    const size_t pairsB_off = pairsA_off + pairs_bytes;
    const size_t need_inplace = pairsA_off + pairs_bytes;      // ~181 MB (proven fits)
    const size_t need_pp      = pairsB_off + pairs_bytes;      // ~341 MB

    if (n_users > (1 << SHIFT) || n_items > (1 << SHIFT) || ws_size < need_inplace) {
        hipMemsetAsync(d_out, 0, (size_t)out_size * sizeof(float), stream);
        lightgcn_scatter_atomic<<<2048, 256, 0, stream>>>(user_emb, item_emb, rows,
                                                          cols, vals, user_out,
                                                          item_out, nnz);
        return;
    }

    const bool use_pp = (ws_size >= need_pp);

    int* counts    = (int*)d_ws;
    int* bases     = counts + Kpad;
    int* cursor    = bases + Kpad;
    int* row_start = cursor + Kpad;            // item rows [0,n_items), then user
    ushort* tblu   = (ushort*)((char*)d_ws + tbl_off);
    ushort* tbli   = tblu + (size_t)n_users * DIM;
    uint2* pairsA  = (uint2*)((char*)d_ws + pairsA_off);
    uint2* pairsB  = (uint2*)((char*)d_ws + pairsB_off);
    uint2* pairsF  = use_pp ? pairsB : pairsA;   // final (sorted) buffer

    to_bf16<<<512, 256, 0, stream>>>(user_emb, n_users * DIM, tblu);
    to_bf16<<<512, 256, 0, stream>>>(item_emb, n_items * DIM, tbli);
    hipMemsetAsync(counts, 0, (size_t)K_all * sizeof(int), stream);

    const size_t hist_bytes = (size_t)K_all * sizeof(int);
    count_hist<<<512, 256, hist_bytes, stream>>>(rows, cols, nnz, K_i, K_all, counts);
    exscan_small<<<1, 1024, 0, stream>>>(counts, K_all, bases, cursor);
    partition_edges<<<(nnz + CHUNK - 1) / CHUNK, 256, hist_bytes, stream>>>(
        rows, cols, vals, nnz, K_i, K_all, cursor, pairsA);
    refine_buckets<<<K_all, RTHREADS, 0, stream>>>(pairsA, pairsF, bases, counts,
                                                   K_i, n_users, n_items, row_start,
                                                   use_pp ? 0 : 1);

    const int blk_i = (int)(((size_t)n_items * 64 + 255) / 256);
    const int blk_u = (int)(((size_t)n_users * 64 + 255) / 256);
    row_accumulate<<<blk_i, 256, 0, stream>>>(tblu, pairsF, bases, counts,
                                              row_start, 0, n_items, item_out);
    row_accumulate<<<blk_u, 256, 0, stream>>>(tbli, pairsF, bases, counts,
                                              row_start + n_items, K_i,
                                              n_users, user_out);
}